// Round 1
// baseline (485.187 us; speedup 1.0000x reference)
//
#include <hip/hip_runtime.h>

// RWKV WKV forward scan.
// B=16, T=2048, D=1024, fp32. One thread per (b,d) chain; serial over T.
// Layout: x[b, t, d] at offset b*T*D + t*D + d. Lane i of a wave owns
// channel (c & 1023) consecutive -> coalesced 256B lines per t-step.

#define TT 2048
#define DD 1024
#define UU 16   // register batch (double-buffered: A/B)

__global__ __launch_bounds__(64) void wkv_fwd(const float* __restrict__ kg,
                                              const float* __restrict__ vg,
                                              const float* __restrict__ wg,
                                              float* __restrict__ og) {
    const int c = blockIdx.x * 64 + threadIdx.x;              // chain id in [0, B*D)
    const size_t base = (size_t)(c >> 10) * (size_t)TT * DD   // b*T*D
                      + (size_t)(c & (DD - 1));               // + d
    const float* kp = kg + base;
    const float* vp = vg + base;
    const float* wp = wg + base;
    float*       op = og + base;

    float kA[UU], vA[UU], wA[UU];   // buffer A
    float kB[UU], vB[UU], wB[UU];   // buffer B

    // prime buffer A with t = 0..U-1
#pragma unroll
    for (int j = 0; j < UU; ++j) {
        const size_t off = (size_t)j * DD;
        kA[j] = kp[off];
        vA[j] = vp[off];
        wA[j] = wp[off];
    }

    float a = 0.0f, b = 0.0f;

    for (int t0 = 0; t0 < TT; t0 += 2 * UU) {
        // prefetch B = [t0+U, t0+2U)  (always valid: TT % (2*UU) == 0)
#pragma unroll
        for (int j = 0; j < UU; ++j) {
            const size_t off = (size_t)(t0 + UU + j) * DD;
            kB[j] = kp[off];
            vB[j] = vp[off];
            wB[j] = wp[off];
        }
        // compute on A = [t0, t0+U)
#pragma unroll
        for (int j = 0; j < UU; ++j) {
            const float ew = __expf(wA[j]);
            const float ek = __expf(kA[j]);
            a = ew * a + ek;
            b = ew * b + ek * vA[j];
            op[(size_t)(t0 + j) * DD] = __fdividef(b, a);
        }
        // prefetch A = [t0+2U, t0+3U) for the next outer iteration
        if (t0 + 2 * UU < TT) {
#pragma unroll
            for (int j = 0; j < UU; ++j) {
                const size_t off = (size_t)(t0 + 2 * UU + j) * DD;
                kA[j] = kp[off];
                vA[j] = vp[off];
                wA[j] = wp[off];
            }
        }
        // compute on B = [t0+U, t0+2U)
#pragma unroll
        for (int j = 0; j < UU; ++j) {
            const float ew = __expf(wB[j]);
            const float ek = __expf(kB[j]);
            a = ew * a + ek;
            b = ew * b + ek * vB[j];
            op[(size_t)(t0 + UU + j) * DD] = __fdividef(b, a);
        }
    }
}

extern "C" void kernel_launch(void* const* d_in, const int* in_sizes, int n_in,
                              void* d_out, int out_size, void* d_ws, size_t ws_size,
                              hipStream_t stream) {
    const float* k = (const float*)d_in[0];
    const float* v = (const float*)d_in[1];
    const float* w = (const float*)d_in[2];
    float* out = (float*)d_out;

    const int channels = 16 * DD;                 // B * D = 16384 chains
    wkv_fwd<<<dim3(channels / 64), dim3(64), 0, stream>>>(k, v, w, out);
}